// Round 1
// 1690.738 us; speedup vs baseline: 1.1667x; 1.1667x over previous
//
#include <hip/hip_runtime.h>
#include <cstdint>

#define D 256
#define TEMP_INV 2.5f
#define LN_EPS 1e-5f

using short8  = __attribute__((ext_vector_type(8))) short;
using floatx4 = __attribute__((ext_vector_type(4))) float;

__device__ __forceinline__ unsigned short f2bf(float f) {
    unsigned u = __builtin_bit_cast(unsigned, f);
    u += 0x7fffu + ((u >> 16) & 1u);   // RNE
    return (unsigned short)(u >> 16);
}

// Exact-GELU via Abramowitz-Stegun 7.1.26 erf (|abs err| <= 1.5e-7):
// ~13 VALU ops incl. hardware v_rcp_f32 / v_exp_f32 vs ~50 for libcall erff.
__device__ __forceinline__ float gelu_f(float v) {
    float x  = v * 0.70710678118f;
    float ax = fabsf(x);
    float t  = __builtin_amdgcn_rcpf(fmaf(0.3275911f, ax, 1.f));
    float p  = fmaf(1.061405429f, t, -1.453152027f);
    p = fmaf(p, t, 1.421413741f);
    p = fmaf(p, t, -0.284496736f);
    p = fmaf(p, t, 0.254829592f);
    p = p * t;
    float e  = __expf(-x * x);
    float er = fmaf(-p, e, 1.f);          // erf(|x|)
    er = copysignf(er, x);
    return 0.5f * v * (1.f + er);
}

// x-tile LDS granule offset (uint4 units). Granule (row=rt*16+m, kt, q) holds
// x[row][kt*32+q*8 .. +8] as 8 bf16. Reads per (rt,kt) are lane-contiguous
// (conflict-free); XOR swizzle spreads the staging writes across banks.
__device__ __forceinline__ int gran_off(int rt, int m, int kt, int q) {
    int swz = (kt * 2 + (q & 1)) & 15;
    return (kt * 4 + rt) * 64 + q * 16 + (m ^ swz);
}

__global__ void k_conv_w1(const float* __restrict__ w1, unsigned short* __restrict__ w1b) {
    int i = (blockIdx.x * 256 + threadIdx.x) * 4;
    float4 v = *(const float4*)(w1 + i);
    ushort4 o;
    o.x = f2bf(v.x); o.y = f2bf(v.y); o.z = f2bf(v.z); o.w = f2bf(v.w);
    *(ushort4*)(w1b + i) = o;
}

__global__ void k_seg_bounds(const int* __restrict__ batch, int* __restrict__ seg,
                             int N, int B) {
    int t = blockIdx.x * 256 + threadIdx.x;
    if (t > B) return;
    int lo = 0, hi = N;
    while (lo < hi) { int mid = (lo + hi) >> 1; if (batch[mid] < t) lo = mid + 1; else hi = mid; }
    seg[t] = lo;
}

// 64 rows/block, 4 waves; wave w computes cols [64w, 64w+64).
// Cross-wave row reduction: per-wave partial writes to red[4][64] (no atomics,
// no zeroing), 3 barriers total.
__global__ __launch_bounds__(256, 4) void k_logits(
    const float* __restrict__ x, const unsigned short* __restrict__ w1b,
    const float* __restrict__ b1, const float* __restrict__ ln1w,
    const float* __restrict__ ln1b, const float* __restrict__ w2,
    float* __restrict__ logits)
{
    __shared__ uint4 ldsX[2048];                 // 32 KB bf16 x-tile
    __shared__ float redS[256], redQ[256], redL[256];   // [wave][row] partials

    const int t = threadIdx.x;
    const int row0 = blockIdx.x * 64;

    // ---- stage x tile fp32 -> bf16 granules ----
    {
        const float4* xf4 = (const float4*)x;
        #pragma unroll
        for (int it = 0; it < 8; ++it) {
            int c = it * 256 + t;                // granule id 0..2047
            int row = c >> 5, j = c & 31;        // j: 8-float chunk in row
            long base = (long)(row0 + row) * 64 + j * 2;
            float4 a = xf4[base], b = xf4[base + 1];
            union { uint4 u; unsigned short s[8]; } g;
            g.s[0] = f2bf(a.x); g.s[1] = f2bf(a.y); g.s[2] = f2bf(a.z); g.s[3] = f2bf(a.w);
            g.s[4] = f2bf(b.x); g.s[5] = f2bf(b.y); g.s[6] = f2bf(b.z); g.s[7] = f2bf(b.w);
            ldsX[gran_off(row >> 4, row & 15, j >> 2, j & 3)] = g.u;
        }
    }
    __syncthreads();

    const int wave = t >> 6, lane = t & 63;
    const int q = lane >> 4, m = lane & 15;

    // per-column constants (issued early; L2-resident, latency hides under MFMA)
    float b1c[4], lwc[4], lbc[4], w2c[4];
    #pragma unroll
    for (int ct = 0; ct < 4; ++ct) {
        int col = wave * 64 + ct * 16 + m;
        b1c[ct] = b1[col]; lwc[ct] = ln1w[col]; lbc[ct] = ln1b[col]; w2c[ct] = w2[col];
    }

    floatx4 acc[4][4];                           // [rt][ct]
    #pragma unroll
    for (int a = 0; a < 4; ++a)
        #pragma unroll
        for (int b = 0; b < 4; ++b)
            acc[a][b] = (floatx4){0.f, 0.f, 0.f, 0.f};

    const uint4* w1b4 = (const uint4*)w1b;       // 8 bf16 per uint4
    #pragma unroll
    for (int kt = 0; kt < 8; ++kt) {
        uint4 afu[4];
        #pragma unroll
        for (int rt = 0; rt < 4; ++rt) afu[rt] = ldsX[gran_off(rt, m, kt, q)];
        #pragma unroll
        for (int ct = 0; ct < 4; ++ct) {
            int col = wave * 64 + ct * 16 + m;   // B-frag: n=lane&15, k=q*8+j
            uint4 bfu = w1b4[col * 32 + kt * 4 + q];
            short8 bfr = __builtin_bit_cast(short8, bfu);
            #pragma unroll
            for (int rt = 0; rt < 4; ++rt)
                acc[rt][ct] = __builtin_amdgcn_mfma_f32_16x16x32_bf16(
                    __builtin_bit_cast(short8, afu[rt]), bfr, acc[rt][ct], 0, 0, 0);
        }
    }

    // ---- phase A: +b1, per-wave row partial sums (regs only, then LDS write) ----
    #pragma unroll
    for (int rt = 0; rt < 4; ++rt) {
        #pragma unroll
        for (int reg = 0; reg < 4; ++reg) {
            float s = 0.f, ss = 0.f;
            #pragma unroll
            for (int ct = 0; ct < 4; ++ct) {
                float v = acc[rt][ct][reg] + b1c[ct];
                acc[rt][ct][reg] = v;
                s += v; ss += v * v;
            }
            #pragma unroll
            for (int off = 1; off < 16; off <<= 1) {
                s  += __shfl_xor(s, off);
                ss += __shfl_xor(ss, off);
            }
            if (m == 0) {
                int r = rt * 16 + q * 4 + reg;
                redS[wave * 64 + r] = s;
                redQ[wave * 64 + r] = ss;
            }
        }
    }
    __syncthreads();

    // ---- phase B: LN + fast GELU + dot W2 ----
    #pragma unroll
    for (int rt = 0; rt < 4; ++rt) {
        #pragma unroll
        for (int reg = 0; reg < 4; ++reg) {
            int r = rt * 16 + q * 4 + reg;
            float sum = redS[r] + redS[64 + r] + redS[128 + r] + redS[192 + r];
            float sq  = redQ[r] + redQ[64 + r] + redQ[128 + r] + redQ[192 + r];
            float mu  = sum * (1.f / 256.f);
            float var = sq * (1.f / 256.f) - mu * mu;
            float rstd = rsqrtf(var + LN_EPS);
            float s = 0.f;
            #pragma unroll
            for (int ct = 0; ct < 4; ++ct) {
                float v = (acc[rt][ct][reg] - mu) * rstd * lwc[ct] + lbc[ct];
                s += gelu_f(v) * w2c[ct];
            }
            #pragma unroll
            for (int off = 1; off < 16; off <<= 1) s += __shfl_xor(s, off);
            if (m == 0) redL[wave * 64 + r] = s;
        }
    }
    __syncthreads();
    if (t < 64) logits[row0 + t] = redL[t] + redL[64 + t] + redL[128 + t] + redL[192 + t];
}

// one wave per segment: max -> exp+sum (stores exp in place) -> scale
__global__ __launch_bounds__(64) void k_segstats(float* __restrict__ w,
                                                 const int* __restrict__ seg) {
    int b = blockIdx.x, lane = threadIdx.x;
    int s = seg[b], e = seg[b + 1], n = e - s;
    if (n <= 0) return;
    float mx = -3.4e38f;
    for (int i = lane; i < n; i += 64) mx = fmaxf(mx, w[s + i]);
    #pragma unroll
    for (int off = 1; off < 64; off <<= 1) mx = fmaxf(mx, __shfl_xor(mx, off));
    float sum = 0.f;
    for (int i = lane; i < n; i += 64) {
        float p = __expf((w[s + i] - mx) * TEMP_INV);
        sum += p;
        w[s + i] = p;
    }
    #pragma unroll
    for (int off = 1; off < 64; off <<= 1) sum += __shfl_xor(sum, off);
    float inv = 1.f / (sum + 1e-6f);
    for (int i = lane; i < n; i += 64) w[s + i] *= inv;
}

// one block per segment: out[b] = sum coef_i * x[i], then LayerNorm.
// Wave w owns rows i = w, w+4, ...; each lane loads float4 (16B/lane, 1KB/wave
// per instruction); 2 independent accumulators; LDS transpose-combine.
__global__ __launch_bounds__(256) void k_pool(
    const float* __restrict__ x, const float* __restrict__ coef,
    const int* __restrict__ seg, const float* __restrict__ ln2w,
    const float* __restrict__ ln2b, float* __restrict__ out)
{
    int b = blockIdx.x, t = threadIdx.x;
    int wave = t >> 6, lane = t & 63;
    int s = seg[b], e = seg[b + 1], n = e - s;

    const float4* xp = (const float4*)x + (long)s * 64 + lane;
    const float* cp = coef + s;

    float4 a0 = {0.f, 0.f, 0.f, 0.f}, a1 = {0.f, 0.f, 0.f, 0.f};
    int i = wave;
    for (; i + 4 < n; i += 8) {
        float c0 = cp[i], c1 = cp[i + 4];
        float4 v0 = xp[(long)i * 64];
        float4 v1 = xp[(long)(i + 4) * 64];
        a0.x = fmaf(c0, v0.x, a0.x); a0.y = fmaf(c0, v0.y, a0.y);
        a0.z = fmaf(c0, v0.z, a0.z); a0.w = fmaf(c0, v0.w, a0.w);
        a1.x = fmaf(c1, v1.x, a1.x); a1.y = fmaf(c1, v1.y, a1.y);
        a1.z = fmaf(c1, v1.z, a1.z); a1.w = fmaf(c1, v1.w, a1.w);
    }
    for (; i < n; i += 4) {
        float c = cp[i];
        float4 v = xp[(long)i * 64];
        a0.x = fmaf(c, v.x, a0.x); a0.y = fmaf(c, v.y, a0.y);
        a0.z = fmaf(c, v.z, a0.z); a0.w = fmaf(c, v.w, a0.w);
    }
    float4 acc4;
    acc4.x = a0.x + a1.x; acc4.y = a0.y + a1.y;
    acc4.z = a0.z + a1.z; acc4.w = a0.w + a1.w;

    __shared__ float part[4][256];
    *(float4*)&part[wave][lane * 4] = acc4;      // contiguous b128, conflict-free
    __syncthreads();
    float acc = part[0][t] + part[1][t] + part[2][t] + part[3][t];

    __shared__ float rb[8];
    float v = acc, vv = acc * acc;
    #pragma unroll
    for (int off = 1; off < 64; off <<= 1) { v += __shfl_xor(v, off); vv += __shfl_xor(vv, off); }
    if (lane == 0) { rb[wave] = v; rb[4 + wave] = vv; }
    __syncthreads();
    float sum = rb[0] + rb[1] + rb[2] + rb[3];
    float sq  = rb[4] + rb[5] + rb[6] + rb[7];
    float mu  = sum * (1.f / (float)D);
    float var = sq * (1.f / (float)D) - mu * mu;
    float rstd = rsqrtf(var + LN_EPS);
    out[(long)b * D + t] = (acc - mu) * rstd * ln2w[t] + ln2b[t];
}

extern "C" void kernel_launch(void* const* d_in, const int* in_sizes, int n_in,
                              void* d_out, int out_size, void* d_ws, size_t ws_size,
                              hipStream_t stream) {
    const float* x    = (const float*)d_in[0];
    const int*   batch= (const int*)d_in[1];
    const float* W1   = (const float*)d_in[2];
    const float* b1   = (const float*)d_in[3];
    const float* ln1w = (const float*)d_in[4];
    const float* ln1b = (const float*)d_in[5];
    const float* W2   = (const float*)d_in[6];
    const float* ln2w = (const float*)d_in[7];
    const float* ln2b = (const float*)d_in[8];
    float* out = (float*)d_out;

    int N = in_sizes[0] / D;          // 1,000,000
    int B = out_size / D;             // 4096

    char* ws = (char*)d_ws;
    unsigned short* w1b = (unsigned short*)ws;                      // 128 KB
    float* wcoef = (float*)(ws + 131072);                           // N floats
    size_t segoff = 131072 + (((size_t)N * 4 + 127) & ~(size_t)127);
    int* seg = (int*)(ws + segoff);                                 // B+1 ints

    k_conv_w1   <<<(D * D) / 1024, 256, 0, stream>>>(W1, w1b);
    k_seg_bounds<<<(B + 256) / 256, 256, 0, stream>>>(batch, seg, N, B);
    k_logits    <<<N / 64, 256, 0, stream>>>(x, w1b, b1, ln1w, ln1b, W2, wcoef);
    k_segstats  <<<B, 64, 0, stream>>>(wcoef, seg);
    k_pool      <<<B, 256, 0, stream>>>(x, wcoef, seg, ln2w, ln2b, out);
}